// Round 9
// baseline (172.359 us; speedup 1.0000x reference)
//
#include <hip/hip_runtime.h>

#define NNODES 50000
#define NEDGES 800000
#define HD 128            // HEADS*OUT_DIM
#define NEG 0.2f
#define MTILE 64
#define LDW 136           // bf16 row stride in LDS
#define MAXD 64           // per-node LDS edge cap in gat_node (== wave width)
#define GEMMB ((NNODES + MTILE - 1) / MTILE) // 782
#define NBINS 196         // ceil(NNODES/256) coarse bins (dst>>8)
#define CAP 5120          // per-bin capacity (mean 4082, +16 sigma)
#define ABLK ((NEDGES + 2047) / 2048)        // 391 bucket blocks
#define APOOLB ((NEDGES / 4 + 255) / 256)    // 782 apool blocks (fused in node)

typedef __attribute__((ext_vector_type(8))) short short8;
typedef __attribute__((ext_vector_type(4))) float floatx4;

static __device__ inline unsigned short f2bf(float f) {
    unsigned u = __float_as_uint(f);
    return (unsigned short)((u + 0x7FFF + ((u >> 16) & 1)) >> 16);
}
static __device__ inline float bf2f(unsigned short u) {
    return __uint_as_float(((unsigned)u) << 16);
}
static __device__ inline float lrelu_exp(float a) {
    a = (a > 0.f) ? a : NEG * a;
    return __expf(a);
}

// ---------------------------------------------------------------------------
// Kernel 1: blocks [0,GEMMB) = 64-row GEMM tile (bf16 MFMA, fused asrc/adst
// dots). Blocks [GEMMB,GEMMB+ABLK) = per-block LDS counting sort of 2048
// edges by coarse bin (dst>>8): hist -> scan -> LDS scatter -> COALESCED dump
// to sbuf + per-block offset table Sg. ZERO global atomics.
// ---------------------------------------------------------------------------
__global__ __launch_bounds__(256, 4) void gat_main(
    const float* __restrict__ x, const float* __restrict__ W,
    const float* __restrict__ att_src, const float* __restrict__ att_dst,
    const int* __restrict__ ei,
    unsigned short* __restrict__ h, float* __restrict__ asrc,
    float* __restrict__ adst, int* __restrict__ Sg, int* __restrict__ sbuf)
{
    __shared__ __align__(16) unsigned short Wl[128 * LDW];    // 34816 B
    const int t = threadIdx.x;

    if (blockIdx.x >= GEMMB) {      // ---- bucket path (local sort) ----
        int* hist = (int*)Wl;       // [256]
        int* sh   = hist + 256;     // [256]
        int* run  = sh + 256;       // [256]
        int* lbuf = run + 256;      // [2048] packed (fine<<16|src)
        const int blk = blockIdx.x - GEMMB;
        const int e0 = blk * 2048 + t * 8;
        const bool act = (e0 < NEDGES);
        const int cnt = (blk == ABLK - 1) ? (NEDGES - blk * 2048) : 2048;
        int4 s0 = make_int4(0, 0, 0, 0), s1 = s0, d0 = s0, d1 = s0;
        if (act) {
            s0 = *(const int4*)(ei + e0);
            s1 = *(const int4*)(ei + e0 + 4);
            d0 = *(const int4*)(ei + NEDGES + e0);
            d1 = *(const int4*)(ei + NEDGES + e0 + 4);
        }
        hist[t] = 0;
        __syncthreads();
        if (act) {
            atomicAdd(&hist[d0.x >> 8], 1); atomicAdd(&hist[d0.y >> 8], 1);
            atomicAdd(&hist[d0.z >> 8], 1); atomicAdd(&hist[d0.w >> 8], 1);
            atomicAdd(&hist[d1.x >> 8], 1); atomicAdd(&hist[d1.y >> 8], 1);
            atomicAdd(&hist[d1.z >> 8], 1); atomicAdd(&hist[d1.w >> 8], 1);
        }
        __syncthreads();
        int hv = hist[t];
        sh[t] = hv;
        __syncthreads();
        for (int off = 1; off < 256; off <<= 1) {
            int u = (t >= off) ? sh[t - off] : 0;
            __syncthreads();
            sh[t] += u;
            __syncthreads();
        }
        int ex = sh[t] - hv;
        run[t] = ex;
        Sg[blk * 257 + t] = ex;                    // coalesced offset table
        if (t == 0) Sg[blk * 257 + 256] = cnt;
        __syncthreads();
        if (act) {
            int ss[8] = {s0.x, s0.y, s0.z, s0.w, s1.x, s1.y, s1.z, s1.w};
            int dd[8] = {d0.x, d0.y, d0.z, d0.w, d1.x, d1.y, d1.z, d1.w};
#pragma unroll
            for (int j = 0; j < 8; j++) {
                int slot = atomicAdd(&run[dd[j] >> 8], 1);  // LDS atomic
                lbuf[slot] = ((dd[j] & 255) << 16) | ss[j];
            }
        }
        __syncthreads();
        for (int i = t; i < cnt; i += 256)          // coalesced dump
            sbuf[blk * 2048 + i] = lbuf[i];
        return;
    }

    // ---- GEMM path ----
    const int rowBase = blockIdx.x * MTILE;

    // W stage: fp32 -> bf16 into LDS
    for (int idx = t * 8; idx < 128 * 128; idx += 2048) {
        int r = idx >> 7, c = idx & 127;
        float4 v0 = *(const float4*)(W + idx);
        float4 v1 = *(const float4*)(W + idx + 4);
        short8 u;
        u[0] = (short)f2bf(v0.x); u[1] = (short)f2bf(v0.y);
        u[2] = (short)f2bf(v0.z); u[3] = (short)f2bf(v0.w);
        u[4] = (short)f2bf(v1.x); u[5] = (short)f2bf(v1.y);
        u[6] = (short)f2bf(v1.z); u[7] = (short)f2bf(v1.w);
        *(short8*)(Wl + r * LDW + c) = u;
    }

    // x A-fragments: global -> registers
    const int wave = t >> 6;
    const int lane = t & 63;
    const int c16  = lane & 15;
    const int quad = lane >> 4;
    const int xr   = rowBase + wave * 16 + c16;
    short8 av[4];
#pragma unroll
    for (int kc = 0; kc < 4; kc++) {
        float4 v0 = make_float4(0.f, 0.f, 0.f, 0.f);
        float4 v1 = v0;
        if (xr < NNODES) {
            const float* p = x + (size_t)xr * 128 + kc * 32 + quad * 8;
            v0 = *(const float4*)p;
            v1 = *(const float4*)(p + 4);
        }
        short8 u;
        u[0] = (short)f2bf(v0.x); u[1] = (short)f2bf(v0.y);
        u[2] = (short)f2bf(v0.z); u[3] = (short)f2bf(v0.w);
        u[4] = (short)f2bf(v1.x); u[5] = (short)f2bf(v1.y);
        u[6] = (short)f2bf(v1.z); u[7] = (short)f2bf(v1.w);
        av[kc] = u;
    }
    __syncthreads();

    floatx4 acc[8];
#pragma unroll
    for (int nt = 0; nt < 8; nt++) acc[nt] = (floatx4)(0.f);

#pragma unroll
    for (int kc = 0; kc < 4; kc++) {
#pragma unroll
        for (int nt = 0; nt < 8; nt++) {
            short8 bv = *(const short8*)(Wl + (nt * 16 + c16) * LDW + kc * 32 + quad * 8);
            acc[nt] = __builtin_amdgcn_mfma_f32_16x16x32_bf16(av[kc], bv, acc[nt], 0, 0, 0);
        }
    }

    float As[8], Ad[8];
#pragma unroll
    for (int nt = 0; nt < 8; nt++) {
        As[nt] = att_src[nt * 16 + c16];
        Ad[nt] = att_dst[nt * 16 + c16];
    }
#pragma unroll
    for (int r = 0; r < 4; r++) {
        const int gr = rowBase + wave * 16 + quad * 4 + r;
#pragma unroll
        for (int hh = 0; hh < 4; hh++) {
            float ps = acc[2 * hh][r] * As[2 * hh] + acc[2 * hh + 1][r] * As[2 * hh + 1];
            float pd = acc[2 * hh][r] * Ad[2 * hh] + acc[2 * hh + 1][r] * Ad[2 * hh + 1];
#pragma unroll
            for (int m = 8; m >= 1; m >>= 1) {
                ps += __shfl_xor(ps, m, 64);
                pd += __shfl_xor(pd, m, 64);
            }
            if (c16 == 0 && gr < NNODES) {
                asrc[gr * 4 + hh] = ps;
                adst[gr * 4 + hh] = pd;
            }
        }
    }

    // epilogue: C bounce through Wl for 16B coalesced h stores
    __syncthreads();
#pragma unroll
    for (int r = 0; r < 4; r++) {
        const int lr = wave * 16 + quad * 4 + r;
#pragma unroll
        for (int nt = 0; nt < 8; nt++)
            Wl[lr * LDW + nt * 16 + c16] = f2bf(acc[nt][r]);
    }
    __syncthreads();
    for (int idx = t * 8; idx < MTILE * 128; idx += 2048) {
        int r = idx >> 7, c = idx & 127;
        int g = rowBase + r;
        if (g < NNODES)
            *(short8*)(h + (size_t)g * HD + c) = *(const short8*)(Wl + r * LDW + c);
    }
}

// ---------------------------------------------------------------------------
// Kernel 2: per coarse bin: gather 391 per-block segments (via Sg) into LDS,
// fine 256-bin hist + scan -> coffB/coffE, LDS scatter grouped by node,
// coalesced CSR dump, and EDGE-PARALLEL per-node exp sums via LDS float
// atomics over the intact ebi[] (r8's serial per-node tail was the regression
// — degree variance on 256 threads; this uses all 1024). -> rsumr.
// ---------------------------------------------------------------------------
__global__ __launch_bounds__(1024) void gat_bin(
    const int* __restrict__ Sg, const int* __restrict__ sbuf,
    const float* __restrict__ asrc, const float* __restrict__ adst,
    int* __restrict__ coffB, int* __restrict__ coffE,
    unsigned short* __restrict__ csr, float* __restrict__ rsumr)
{
    __shared__ int s0arr[391];
    __shared__ int segoff[391];
    __shared__ int ebi[CAP];
    __shared__ unsigned short ebs[CAP];
    __shared__ int hist[256], run[256], sh[512];
    __shared__ float sum4[256 * 4];            // per-node per-head exp sums
    const int t = threadIdx.x;
    const int b = blockIdx.x;

    int s0v = 0, lenv = 0;
    if (t < 391) {
        s0v = Sg[t * 257 + b];
        lenv = Sg[t * 257 + b + 1] - s0v;
        s0arr[t] = s0v;
    }
    if (t < 256) hist[t] = 0;
    sum4[t] = 0.f;                              // 1024 threads == 256*4 slots
    // scan seglen over 512 slots -> exclusive segoff, total c_b
    if (t < 512) sh[t] = (t < 391) ? lenv : 0;
    __syncthreads();
    for (int off = 1; off < 512; off <<= 1) {
        int u = (t < 512 && t >= off) ? sh[t - off] : 0;
        __syncthreads();
        if (t < 512) sh[t] += u;
        __syncthreads();
    }
    if (t < 391) segoff[t] = sh[t] - lenv;
    __syncthreads();
    const int c_b = sh[390];

    // gather: binary search containing segment per edge slot
    for (int i = t; i < c_b; i += 1024) {
        int lo = 0, hi = 390;
        while (lo < hi) {
            int mid = (lo + hi + 1) >> 1;
            if (segoff[mid] <= i) lo = mid; else hi = mid - 1;
        }
        int e = sbuf[lo * 2048 + s0arr[lo] + (i - segoff[lo])];
        ebi[i] = e;
        atomicAdd(&hist[(e >> 16) & 255], 1);      // LDS atomic
    }
    __syncthreads();

    // scan fine hist -> coffB/coffE + running offsets
    int hv = (t < 256) ? hist[t] : 0;
    if (t < 256) sh[t] = hv;
    __syncthreads();
    for (int off = 1; off < 256; off <<= 1) {
        int u = (t < 256 && t >= off) ? sh[t - off] : 0;
        __syncthreads();
        if (t < 256) sh[t] += u;
        __syncthreads();
    }
    if (t < 256) {
        int ex = sh[t] - hv;
        run[t] = ex;
        int n = b * 256 + t;
        if (n < NNODES) {
            coffB[n] = b * CAP + ex;
            coffE[n] = b * CAP + ex + hv;
        }
    }
    __syncthreads();

    // scatter grouped-by-node into LDS
    for (int i = t; i < c_b; i += 1024) {
        int e = ebi[i];
        int slot = atomicAdd(&run[(e >> 16) & 255], 1);     // LDS atomic
        ebs[slot] = (unsigned short)(e & 0xFFFF);
    }
    __syncthreads();

    // coalesced CSR dump + edge-parallel exp-sum accumulation (all 1024 thr)
    for (int i = t; i < c_b; i += 1024)
        csr[(size_t)b * CAP + i] = ebs[i];
    for (int i = t; i < c_b; i += 1024) {
        int e = ebi[i];
        int f = (e >> 16) & 255;
        int s = e & 0xFFFF;
        float4 a  = *(const float4*)(asrc + s * 4);
        float4 bn = *(const float4*)(adst + (b * 256 + f) * 4);
        atomicAdd(&sum4[f * 4 + 0], lrelu_exp(a.x + bn.x));
        atomicAdd(&sum4[f * 4 + 1], lrelu_exp(a.y + bn.y));
        atomicAdd(&sum4[f * 4 + 2], lrelu_exp(a.z + bn.z));
        atomicAdd(&sum4[f * 4 + 3], lrelu_exp(a.w + bn.w));
    }
    __syncthreads();

    if (t < 256) {
        int n = b * 256 + t;
        if (n < NNODES) {
            float4 r4;
            r4.x = 1.f / (sum4[t * 4 + 0] + 1e-16f);
            r4.y = 1.f / (sum4[t * 4 + 1] + 1e-16f);
            r4.z = 1.f / (sum4[t * 4 + 2] + 1e-16f);
            r4.w = 1.f / (sum4[t * 4 + 3] + 1e-16f);
            *(float4*)(rsumr + n * 4) = r4;
        }
    }
}

// ---------------------------------------------------------------------------
// Kernel 3 (fused node + apool): blocks [0,APOOLB) = streaming alpha_pooled
// (pure BW, interleaves with latency-bound node waves); blocks [APOOLB,...)
// = per-node aggregation (r6/r8 structure), 4 nodes/block, 64 lanes/node;
// normalization precomputed in gat_bin (rsumr) so h-row loads issue behind
// only a csr read + one exp chain.
// ---------------------------------------------------------------------------
static __device__ inline float apool1(
    int s, int d, const float* __restrict__ asrc,
    const float* __restrict__ adst, const float* __restrict__ rsumr)
{
    float4 a = *(const float4*)(asrc + s * 4);
    float4 b = *(const float4*)(adst + d * 4);
    float4 r = *(const float4*)(rsumr + d * 4);
    return 0.25f * (lrelu_exp(a.x + b.x) * r.x + lrelu_exp(a.y + b.y) * r.y +
                    lrelu_exp(a.z + b.z) * r.z + lrelu_exp(a.w + b.w) * r.w);
}

__global__ __launch_bounds__(256, 8) void gat_node(
    const int* __restrict__ coffB, const int* __restrict__ coffE,
    const unsigned short* __restrict__ csr,
    const float* __restrict__ asrc, const float* __restrict__ adst,
    const unsigned short* __restrict__ h, const float* __restrict__ bias,
    float* __restrict__ out, const float* __restrict__ rsumr,
    const int* __restrict__ ei, float* __restrict__ apool)
{
    __shared__ unsigned short sh_src[4 * MAXD];
    __shared__ float sh_w[4 * MAXD * 4];
    const int t = threadIdx.x;

    if (blockIdx.x < APOOLB) {          // ---- apool path (streaming) ----
        int e0 = (blockIdx.x * 256 + t) * 4;
        if (e0 >= NEDGES) return;
        int4 s = *(const int4*)(ei + e0);
        int4 d = *(const int4*)(ei + NEDGES + e0);
        float4 r;
        r.x = apool1(s.x, d.x, asrc, adst, rsumr);
        r.y = apool1(s.y, d.y, asrc, adst, rsumr);
        r.z = apool1(s.z, d.z, asrc, adst, rsumr);
        r.w = apool1(s.w, d.w, asrc, adst, rsumr);
        *(float4*)(apool + e0) = r;
        return;
    }

    // ---- node path ----
    const int w = t >> 6;                  // node slot (== wave id)
    const int lane = t & 63;
    const int n = (blockIdx.x - APOOLB) * 4 + w;   // 12500*4 == NNODES
    const int beg = coffB[n], end = coffE[n];
    const int deg = end - beg;
    const int lim = (deg < MAXD) ? deg : MAXD;
    const int base = w * MAXD;

    const float4 rs4 = *(const float4*)(rsumr + n * 4);    // L2-hot

    // phase 1: one edge per lane — exp weights -> LDS stash (wave-synchronous)
    if (lane < lim) {
        int s = csr[beg + lane];
        const float4 bn = *(const float4*)(adst + n * 4);
        float4 a = *(const float4*)(asrc + s * 4);
        float4 wv;
        wv.x = lrelu_exp(a.x + bn.x);
        wv.y = lrelu_exp(a.y + bn.y);
        wv.z = lrelu_exp(a.z + bn.z);
        wv.w = lrelu_exp(a.w + bn.w);
        sh_src[base + lane] = (unsigned short)s;
        *(float4*)(sh_w + (base + lane) * 4) = wv;
    }

    // phase 2: 4-edge / ushort8 gather
    const int quad = lane >> 4;       // which edge of the quartet
    const int i16  = lane & 15;       // 8-elem chunk of the row
    const int head = i16 >> 2;
    const float rsel = (head == 0) ? rs4.x : (head == 1) ? rs4.y
                      : (head == 2) ? rs4.z : rs4.w;

    float accA[8], accB[8];
#pragma unroll
    for (int m = 0; m < 8; m++) { accA[m] = 0.f; accB[m] = 0.f; }

    int j = 0;
    for (; j + 16 <= lim; j += 16) {
        int e0 = j + quad, e1 = j + 4 + quad, e2 = j + 8 + quad, e3 = j + 12 + quad;
        int s0 = sh_src[base + e0];
        int s1 = sh_src[base + e1];
        int s2 = sh_src[base + e2];
        int s3 = sh_src[base + e3];
        float w0 = sh_w[(base + e0) * 4 + head] * rsel;
        float w1 = sh_w[(base + e1) * 4 + head] * rsel;
        float w2 = sh_w[(base + e2) * 4 + head] * rsel;
        float w3 = sh_w[(base + e3) * 4 + head] * rsel;
        short8 u0 = *(const short8*)(h + (size_t)s0 * HD + i16 * 8);
        short8 u1 = *(const short8*)(h + (size_t)s1 * HD + i16 * 8);
        short8 u2 = *(const short8*)(h + (size_t)s2 * HD + i16 * 8);
        short8 u3 = *(const short8*)(h + (size_t)s3 * HD + i16 * 8);
#pragma unroll
        for (int m = 0; m < 8; m++) {
            accA[m] = fmaf(bf2f((unsigned short)u0[m]), w0, accA[m]);
            accB[m] = fmaf(bf2f((unsigned short)u1[m]), w1, accB[m]);
            accA[m] = fmaf(bf2f((unsigned short)u2[m]), w2, accA[m]);
            accB[m] = fmaf(bf2f((unsigned short)u3[m]), w3, accB[m]);
        }
    }
    for (; j + 4 <= lim; j += 4) {
        int e0 = j + quad;
        int s0 = sh_src[base + e0];
        float w0 = sh_w[(base + e0) * 4 + head] * rsel;
        short8 u0 = *(const short8*)(h + (size_t)s0 * HD + i16 * 8);
#pragma unroll
        for (int m = 0; m < 8; m++)
            accA[m] = fmaf(bf2f((unsigned short)u0[m]), w0, accA[m]);
    }
    if (quad < lim - j) {             // tail (rem in {1,2,3})
        int s0 = sh_src[base + j + quad];
        float w0 = sh_w[(base + j + quad) * 4 + head] * rsel;
        short8 u0 = *(const short8*)(h + (size_t)s0 * HD + i16 * 8);
#pragma unroll
        for (int m = 0; m < 8; m++)
            accA[m] = fmaf(bf2f((unsigned short)u0[m]), w0, accA[m]);
    }
    // rare overflow fallback (deg > MAXD): recompute weight from asrc
    if (deg > MAXD) {
        const float4 bn = *(const float4*)(adst + n * 4);
        const float bnh = (head == 0) ? bn.x : (head == 1) ? bn.y
                         : (head == 2) ? bn.z : bn.w;
        for (int jj = beg + MAXD + quad; jj < end; jj += 4) {
            int s0 = csr[jj];
            float w0 = lrelu_exp(asrc[s0 * 4 + head] + bnh) * rsel;
            short8 u0 = *(const short8*)(h + (size_t)s0 * HD + i16 * 8);
#pragma unroll
            for (int m = 0; m < 8; m++)
                accA[m] = fmaf(bf2f((unsigned short)u0[m]), w0, accA[m]);
        }
    }

#pragma unroll
    for (int m = 0; m < 8; m++) {
        accA[m] += accB[m];
        accA[m] += __shfl_xor(accA[m], 16, 64);
        accA[m] += __shfl_xor(accA[m], 32, 64);
    }
    // quads 0/1 store the two float4 halves of this chunk (constant indices)
    if (quad < 2) {
        const float4 b4 = *(const float4*)(bias + i16 * 8 + quad * 4);
        float4 st;
        if (quad == 0) {
            st.x = accA[0] + b4.x; st.y = accA[1] + b4.y;
            st.z = accA[2] + b4.z; st.w = accA[3] + b4.w;
        } else {
            st.x = accA[4] + b4.x; st.y = accA[5] + b4.y;
            st.z = accA[6] + b4.z; st.w = accA[7] + b4.w;
        }
        *(float4*)(out + (size_t)n * HD + i16 * 8 + quad * 4) = st;
    }
}

// ---------------------------------------------------------------------------
extern "C" void kernel_launch(void* const* d_in, const int* in_sizes, int n_in,
                              void* d_out, int out_size, void* d_ws, size_t ws_size,
                              hipStream_t stream)
{
    const float* x       = (const float*)d_in[0];
    const int*   ei      = (const int*)d_in[1];
    const float* W       = (const float*)d_in[2];
    const float* att_src = (const float*)d_in[3];
    const float* att_dst = (const float*)d_in[4];
    const float* bias    = (const float*)d_in[5];

    float* out   = (float*)d_out;                    // (N,128)
    float* apool = out + (size_t)NNODES * HD;        // (E,)

    // workspace layout
    unsigned short* h = (unsigned short*)d_ws;            // N*128 bf16
    float* asrc  = (float*)(h + (size_t)NNODES * HD);     // N*4
    float* adst  = asrc + NNODES * 4;                     // N*4
    float* rsumr = adst + NNODES * 4;                     // N*4
    int*   Sg    = (int*)(rsumr + NNODES * 4);            // ABLK*257
    int*   coffB = Sg + ABLK * 257 + 4;                   // N
    int*   coffE = coffB + NNODES + 4;                    // N
    int*   sbuf  = coffE + NNODES + 4;                    // ABLK*2048
    unsigned short* csr = (unsigned short*)(sbuf + (size_t)ABLK * 2048); // NBINS*CAP

    gat_main<<<GEMMB + ABLK, 256, 0, stream>>>(
        x, W, att_src, att_dst, ei, h, asrc, adst, Sg, sbuf);
    gat_bin<<<NBINS, 1024, 0, stream>>>(
        Sg, sbuf, asrc, adst, coffB, coffE, csr, rsumr);
    gat_node<<<APOOLB + NNODES / 4, 256, 0, stream>>>(
        coffB, coffE, csr, asrc, adst, h, bias, out, rsumr, ei, apool);
}

// Round 10
// 160.448 us; speedup vs baseline: 1.0742x; 1.0742x over previous
//
#include <hip/hip_runtime.h>

#define NNODES 50000
#define NEDGES 800000
#define HD 128            // HEADS*OUT_DIM
#define NEG 0.2f
#define MTILE 64
#define LDW 136           // bf16 row stride in LDS
#define MAXD 64           // per-node LDS edge cap in gat_node (== wave width)
#define GEMMB ((NNODES + MTILE - 1) / MTILE) // 782
#define NBINS 196         // ceil(NNODES/256) coarse bins (dst>>8)
#define CAP 5120          // per-bin capacity (mean 4082, +16 sigma)
#define ABLK ((NEDGES + 2047) / 2048)        // 391 bucket blocks
#define NODEB (NNODES / 4)                   // 12500 node blocks
#define APOOLB ((NEDGES / 4 + 255) / 256)    // 782 apool blocks (tail of node)

typedef __attribute__((ext_vector_type(8))) short short8;
typedef __attribute__((ext_vector_type(4))) float floatx4;

static __device__ inline unsigned short f2bf(float f) {
    unsigned u = __float_as_uint(f);
    return (unsigned short)((u + 0x7FFF + ((u >> 16) & 1)) >> 16);
}
static __device__ inline float bf2f(unsigned short u) {
    return __uint_as_float(((unsigned)u) << 16);
}
static __device__ inline float lrelu_exp(float a) {
    a = (a > 0.f) ? a : NEG * a;
    return __expf(a);
}

// ---------------------------------------------------------------------------
// Kernel 1: blocks [0,GEMMB) = 64-row GEMM tile (bf16 MFMA, fused asrc/adst
// dots). Blocks [GEMMB,GEMMB+ABLK) = per-block LDS counting sort of 2048
// edges by coarse bin (dst>>8): hist -> scan -> LDS scatter -> COALESCED dump
// to sbuf + per-block offset table Sg. ZERO global atomics.
// ---------------------------------------------------------------------------
__global__ __launch_bounds__(256, 4) void gat_main(
    const float* __restrict__ x, const float* __restrict__ W,
    const float* __restrict__ att_src, const float* __restrict__ att_dst,
    const int* __restrict__ ei,
    unsigned short* __restrict__ h, float* __restrict__ asrc,
    float* __restrict__ adst, int* __restrict__ Sg, int* __restrict__ sbuf)
{
    __shared__ __align__(16) unsigned short Wl[128 * LDW];    // 34816 B
    const int t = threadIdx.x;

    if (blockIdx.x >= GEMMB) {      // ---- bucket path (local sort) ----
        int* hist = (int*)Wl;       // [256]
        int* sh   = hist + 256;     // [256]
        int* run  = sh + 256;       // [256]
        int* lbuf = run + 256;      // [2048] packed (fine<<16|src)
        const int blk = blockIdx.x - GEMMB;
        const int e0 = blk * 2048 + t * 8;
        const bool act = (e0 < NEDGES);
        const int cnt = (blk == ABLK - 1) ? (NEDGES - blk * 2048) : 2048;
        int4 s0 = make_int4(0, 0, 0, 0), s1 = s0, d0 = s0, d1 = s0;
        if (act) {
            s0 = *(const int4*)(ei + e0);
            s1 = *(const int4*)(ei + e0 + 4);
            d0 = *(const int4*)(ei + NEDGES + e0);
            d1 = *(const int4*)(ei + NEDGES + e0 + 4);
        }
        hist[t] = 0;
        __syncthreads();
        if (act) {
            atomicAdd(&hist[d0.x >> 8], 1); atomicAdd(&hist[d0.y >> 8], 1);
            atomicAdd(&hist[d0.z >> 8], 1); atomicAdd(&hist[d0.w >> 8], 1);
            atomicAdd(&hist[d1.x >> 8], 1); atomicAdd(&hist[d1.y >> 8], 1);
            atomicAdd(&hist[d1.z >> 8], 1); atomicAdd(&hist[d1.w >> 8], 1);
        }
        __syncthreads();
        int hv = hist[t];
        sh[t] = hv;
        __syncthreads();
        for (int off = 1; off < 256; off <<= 1) {
            int u = (t >= off) ? sh[t - off] : 0;
            __syncthreads();
            sh[t] += u;
            __syncthreads();
        }
        int ex = sh[t] - hv;
        run[t] = ex;
        Sg[blk * 257 + t] = ex;                    // coalesced offset table
        if (t == 0) Sg[blk * 257 + 256] = cnt;
        __syncthreads();
        if (act) {
            int ss[8] = {s0.x, s0.y, s0.z, s0.w, s1.x, s1.y, s1.z, s1.w};
            int dd[8] = {d0.x, d0.y, d0.z, d0.w, d1.x, d1.y, d1.z, d1.w};
#pragma unroll
            for (int j = 0; j < 8; j++) {
                int slot = atomicAdd(&run[dd[j] >> 8], 1);  // LDS atomic
                lbuf[slot] = ((dd[j] & 255) << 16) | ss[j];
            }
        }
        __syncthreads();
        for (int i = t; i < cnt; i += 256)          // coalesced dump
            sbuf[blk * 2048 + i] = lbuf[i];
        return;
    }

    // ---- GEMM path ----
    const int rowBase = blockIdx.x * MTILE;

    // W stage: fp32 -> bf16 into LDS
    for (int idx = t * 8; idx < 128 * 128; idx += 2048) {
        int r = idx >> 7, c = idx & 127;
        float4 v0 = *(const float4*)(W + idx);
        float4 v1 = *(const float4*)(W + idx + 4);
        short8 u;
        u[0] = (short)f2bf(v0.x); u[1] = (short)f2bf(v0.y);
        u[2] = (short)f2bf(v0.z); u[3] = (short)f2bf(v0.w);
        u[4] = (short)f2bf(v1.x); u[5] = (short)f2bf(v1.y);
        u[6] = (short)f2bf(v1.z); u[7] = (short)f2bf(v1.w);
        *(short8*)(Wl + r * LDW + c) = u;
    }

    // x A-fragments: global -> registers
    const int wave = t >> 6;
    const int lane = t & 63;
    const int c16  = lane & 15;
    const int quad = lane >> 4;
    const int xr   = rowBase + wave * 16 + c16;
    short8 av[4];
#pragma unroll
    for (int kc = 0; kc < 4; kc++) {
        float4 v0 = make_float4(0.f, 0.f, 0.f, 0.f);
        float4 v1 = v0;
        if (xr < NNODES) {
            const float* p = x + (size_t)xr * 128 + kc * 32 + quad * 8;
            v0 = *(const float4*)p;
            v1 = *(const float4*)(p + 4);
        }
        short8 u;
        u[0] = (short)f2bf(v0.x); u[1] = (short)f2bf(v0.y);
        u[2] = (short)f2bf(v0.z); u[3] = (short)f2bf(v0.w);
        u[4] = (short)f2bf(v1.x); u[5] = (short)f2bf(v1.y);
        u[6] = (short)f2bf(v1.z); u[7] = (short)f2bf(v1.w);
        av[kc] = u;
    }
    __syncthreads();

    floatx4 acc[8];
#pragma unroll
    for (int nt = 0; nt < 8; nt++) acc[nt] = (floatx4)(0.f);

#pragma unroll
    for (int kc = 0; kc < 4; kc++) {
#pragma unroll
        for (int nt = 0; nt < 8; nt++) {
            short8 bv = *(const short8*)(Wl + (nt * 16 + c16) * LDW + kc * 32 + quad * 8);
            acc[nt] = __builtin_amdgcn_mfma_f32_16x16x32_bf16(av[kc], bv, acc[nt], 0, 0, 0);
        }
    }

    float As[8], Ad[8];
#pragma unroll
    for (int nt = 0; nt < 8; nt++) {
        As[nt] = att_src[nt * 16 + c16];
        Ad[nt] = att_dst[nt * 16 + c16];
    }
#pragma unroll
    for (int r = 0; r < 4; r++) {
        const int gr = rowBase + wave * 16 + quad * 4 + r;
#pragma unroll
        for (int hh = 0; hh < 4; hh++) {
            float ps = acc[2 * hh][r] * As[2 * hh] + acc[2 * hh + 1][r] * As[2 * hh + 1];
            float pd = acc[2 * hh][r] * Ad[2 * hh] + acc[2 * hh + 1][r] * Ad[2 * hh + 1];
#pragma unroll
            for (int m = 8; m >= 1; m >>= 1) {
                ps += __shfl_xor(ps, m, 64);
                pd += __shfl_xor(pd, m, 64);
            }
            if (c16 == 0 && gr < NNODES) {
                asrc[gr * 4 + hh] = ps;
                adst[gr * 4 + hh] = pd;
            }
        }
    }

    // epilogue: C bounce through Wl for 16B coalesced h stores
    __syncthreads();
#pragma unroll
    for (int r = 0; r < 4; r++) {
        const int lr = wave * 16 + quad * 4 + r;
#pragma unroll
        for (int nt = 0; nt < 8; nt++)
            Wl[lr * LDW + nt * 16 + c16] = f2bf(acc[nt][r]);
    }
    __syncthreads();
    for (int idx = t * 8; idx < MTILE * 128; idx += 2048) {
        int r = idx >> 7, c = idx & 127;
        int g = rowBase + r;
        if (g < NNODES)
            *(short8*)(h + (size_t)g * HD + c) = *(const short8*)(Wl + r * LDW + c);
    }
}

// ---------------------------------------------------------------------------
// Kernel 2: per coarse bin: gather 391 per-block segments (via Sg) into LDS,
// fine 256-bin hist + scan -> coffB/coffE, LDS scatter grouped by node,
// coalesced CSR dump, then per-node exp sums with FOUR THREADS PER NODE over
// the grouped ebs[] (no LDS atomics, no serial tail — r9's 4-atomics/edge
// hotspot and r8's 256-thread serial loop were both regressions). -> rsumr.
// ---------------------------------------------------------------------------
__global__ __launch_bounds__(1024) void gat_bin(
    const int* __restrict__ Sg, const int* __restrict__ sbuf,
    const float* __restrict__ asrc, const float* __restrict__ adst,
    int* __restrict__ coffB, int* __restrict__ coffE,
    unsigned short* __restrict__ csr, float* __restrict__ rsumr)
{
    __shared__ int s0arr[391];
    __shared__ int segoff[391];
    __shared__ int ebi[CAP];
    __shared__ unsigned short ebs[CAP];
    __shared__ int hist[256], run[256], sh[512];
    __shared__ float4 psum[1024];              // 16 KB partial sums
    const int t = threadIdx.x;
    const int b = blockIdx.x;

    int s0v = 0, lenv = 0;
    if (t < 391) {
        s0v = Sg[t * 257 + b];
        lenv = Sg[t * 257 + b + 1] - s0v;
        s0arr[t] = s0v;
    }
    if (t < 256) hist[t] = 0;
    // scan seglen over 512 slots -> exclusive segoff, total c_b
    if (t < 512) sh[t] = (t < 391) ? lenv : 0;
    __syncthreads();
    for (int off = 1; off < 512; off <<= 1) {
        int u = (t < 512 && t >= off) ? sh[t - off] : 0;
        __syncthreads();
        if (t < 512) sh[t] += u;
        __syncthreads();
    }
    if (t < 391) segoff[t] = sh[t] - lenv;
    __syncthreads();
    const int c_b = sh[390];

    // gather: binary search containing segment per edge slot
    for (int i = t; i < c_b; i += 1024) {
        int lo = 0, hi = 390;
        while (lo < hi) {
            int mid = (lo + hi + 1) >> 1;
            if (segoff[mid] <= i) lo = mid; else hi = mid - 1;
        }
        int e = sbuf[lo * 2048 + s0arr[lo] + (i - segoff[lo])];
        ebi[i] = e;
        atomicAdd(&hist[(e >> 16) & 255], 1);      // LDS atomic
    }
    __syncthreads();

    // scan fine hist -> coffB/coffE + running offsets
    int hv = (t < 256) ? hist[t] : 0;
    if (t < 256) sh[t] = hv;
    __syncthreads();
    for (int off = 1; off < 256; off <<= 1) {
        int u = (t < 256 && t >= off) ? sh[t - off] : 0;
        __syncthreads();
        if (t < 256) sh[t] += u;
        __syncthreads();
    }
    if (t < 256) {
        int ex = sh[t] - hv;
        run[t] = ex;
        int n = b * 256 + t;
        if (n < NNODES) {
            coffB[n] = b * CAP + ex;
            coffE[n] = b * CAP + ex + hv;
        }
    }
    __syncthreads();

    // scatter grouped-by-node into LDS (after this, run[f] == node end)
    for (int i = t; i < c_b; i += 1024) {
        int e = ebi[i];
        int slot = atomicAdd(&run[(e >> 16) & 255], 1);     // LDS atomic
        ebs[slot] = (unsigned short)(e & 0xFFFF);
    }
    __syncthreads();

    // coalesced CSR dump
    for (int i = t; i < c_b; i += 1024)
        csr[(size_t)b * CAP + i] = ebs[i];

    // per-node exp sums: 4 threads per node over grouped ebs (balanced)
    {
        const int nl  = t >> 2;             // local node 0..255
        const int sub = t & 3;
        const int n2  = b * 256 + nl;
        const int eE2 = run[nl];
        const int eB2 = eE2 - hist[nl];
        float4 bn = make_float4(0.f, 0.f, 0.f, 0.f);
        if (n2 < NNODES) bn = *(const float4*)(adst + n2 * 4);
        float4 ps = make_float4(0.f, 0.f, 0.f, 0.f);
        for (int i = eB2 + sub; i < eE2; i += 4) {
            int s = ebs[i];
            float4 a = *(const float4*)(asrc + s * 4);
            ps.x += lrelu_exp(a.x + bn.x);
            ps.y += lrelu_exp(a.y + bn.y);
            ps.z += lrelu_exp(a.z + bn.z);
            ps.w += lrelu_exp(a.w + bn.w);
        }
        psum[t] = ps;
    }
    __syncthreads();
    if (t < 256) {
        int n = b * 256 + t;
        if (n < NNODES) {
            float4 p0 = psum[t * 4 + 0];
            float4 p1 = psum[t * 4 + 1];
            float4 p2 = psum[t * 4 + 2];
            float4 p3 = psum[t * 4 + 3];
            float4 r4;
            r4.x = 1.f / (p0.x + p1.x + p2.x + p3.x + 1e-16f);
            r4.y = 1.f / (p0.y + p1.y + p2.y + p3.y + 1e-16f);
            r4.z = 1.f / (p0.z + p1.z + p2.z + p3.z + 1e-16f);
            r4.w = 1.f / (p0.w + p1.w + p2.w + p3.w + 1e-16f);
            *(float4*)(rsumr + n * 4) = r4;
        }
    }
}

// ---------------------------------------------------------------------------
// Kernel 3 (fused node + apool): blocks [0,NODEB) = per-node aggregation
// (r6/r9 structure, 4 nodes/block, 64 lanes/node; normalization precomputed
// in gat_bin). Blocks [NODEB,NODEB+APOOLB) = streaming alpha_pooled — short
// BW-bound blocks dispatched LAST so they fill tail bubbles as the
// latency-bound node blocks retire.
// ---------------------------------------------------------------------------
static __device__ inline float apool1(
    int s, int d, const float* __restrict__ asrc,
    const float* __restrict__ adst, const float* __restrict__ rsumr)
{
    float4 a = *(const float4*)(asrc + s * 4);
    float4 b = *(const float4*)(adst + d * 4);
    float4 r = *(const float4*)(rsumr + d * 4);
    return 0.25f * (lrelu_exp(a.x + b.x) * r.x + lrelu_exp(a.y + b.y) * r.y +
                    lrelu_exp(a.z + b.z) * r.z + lrelu_exp(a.w + b.w) * r.w);
}

__global__ __launch_bounds__(256, 8) void gat_node(
    const int* __restrict__ coffB, const int* __restrict__ coffE,
    const unsigned short* __restrict__ csr,
    const float* __restrict__ asrc, const float* __restrict__ adst,
    const unsigned short* __restrict__ h, const float* __restrict__ bias,
    float* __restrict__ out, const float* __restrict__ rsumr,
    const int* __restrict__ ei, float* __restrict__ apool)
{
    __shared__ unsigned short sh_src[4 * MAXD];
    __shared__ float sh_w[4 * MAXD * 4];
    const int t = threadIdx.x;

    if (blockIdx.x >= NODEB) {          // ---- apool path (streaming tail) ----
        int e0 = ((blockIdx.x - NODEB) * 256 + t) * 4;
        if (e0 >= NEDGES) return;
        int4 s = *(const int4*)(ei + e0);
        int4 d = *(const int4*)(ei + NEDGES + e0);
        float4 r;
        r.x = apool1(s.x, d.x, asrc, adst, rsumr);
        r.y = apool1(s.y, d.y, asrc, adst, rsumr);
        r.z = apool1(s.z, d.z, asrc, adst, rsumr);
        r.w = apool1(s.w, d.w, asrc, adst, rsumr);
        *(float4*)(apool + e0) = r;
        return;
    }

    // ---- node path ----
    const int w = t >> 6;                  // node slot (== wave id)
    const int lane = t & 63;
    const int n = blockIdx.x * 4 + w;      // 12500*4 == NNODES
    const int beg = coffB[n], end = coffE[n];
    const int deg = end - beg;
    const int lim = (deg < MAXD) ? deg : MAXD;
    const int base = w * MAXD;

    const float4 rs4 = *(const float4*)(rsumr + n * 4);    // L2-hot

    // phase 1: one edge per lane — exp weights -> LDS stash (wave-synchronous)
    if (lane < lim) {
        int s = csr[beg + lane];
        const float4 bn = *(const float4*)(adst + n * 4);
        float4 a = *(const float4*)(asrc + s * 4);
        float4 wv;
        wv.x = lrelu_exp(a.x + bn.x);
        wv.y = lrelu_exp(a.y + bn.y);
        wv.z = lrelu_exp(a.z + bn.z);
        wv.w = lrelu_exp(a.w + bn.w);
        sh_src[base + lane] = (unsigned short)s;
        *(float4*)(sh_w + (base + lane) * 4) = wv;
    }

    // phase 2: 4-edge / ushort8 gather
    const int quad = lane >> 4;       // which edge of the quartet
    const int i16  = lane & 15;       // 8-elem chunk of the row
    const int head = i16 >> 2;
    const float rsel = (head == 0) ? rs4.x : (head == 1) ? rs4.y
                      : (head == 2) ? rs4.z : rs4.w;

    float accA[8], accB[8];
#pragma unroll
    for (int m = 0; m < 8; m++) { accA[m] = 0.f; accB[m] = 0.f; }

    int j = 0;
    for (; j + 16 <= lim; j += 16) {
        int e0 = j + quad, e1 = j + 4 + quad, e2 = j + 8 + quad, e3 = j + 12 + quad;
        int s0 = sh_src[base + e0];
        int s1 = sh_src[base + e1];
        int s2 = sh_src[base + e2];
        int s3 = sh_src[base + e3];
        float w0 = sh_w[(base + e0) * 4 + head] * rsel;
        float w1 = sh_w[(base + e1) * 4 + head] * rsel;
        float w2 = sh_w[(base + e2) * 4 + head] * rsel;
        float w3 = sh_w[(base + e3) * 4 + head] * rsel;
        short8 u0 = *(const short8*)(h + (size_t)s0 * HD + i16 * 8);
        short8 u1 = *(const short8*)(h + (size_t)s1 * HD + i16 * 8);
        short8 u2 = *(const short8*)(h + (size_t)s2 * HD + i16 * 8);
        short8 u3 = *(const short8*)(h + (size_t)s3 * HD + i16 * 8);
#pragma unroll
        for (int m = 0; m < 8; m++) {
            accA[m] = fmaf(bf2f((unsigned short)u0[m]), w0, accA[m]);
            accB[m] = fmaf(bf2f((unsigned short)u1[m]), w1, accB[m]);
            accA[m] = fmaf(bf2f((unsigned short)u2[m]), w2, accA[m]);
            accB[m] = fmaf(bf2f((unsigned short)u3[m]), w3, accB[m]);
        }
    }
    for (; j + 4 <= lim; j += 4) {
        int e0 = j + quad;
        int s0 = sh_src[base + e0];
        float w0 = sh_w[(base + e0) * 4 + head] * rsel;
        short8 u0 = *(const short8*)(h + (size_t)s0 * HD + i16 * 8);
#pragma unroll
        for (int m = 0; m < 8; m++)
            accA[m] = fmaf(bf2f((unsigned short)u0[m]), w0, accA[m]);
    }
    if (quad < lim - j) {             // tail (rem in {1,2,3})
        int s0 = sh_src[base + j + quad];
        float w0 = sh_w[(base + j + quad) * 4 + head] * rsel;
        short8 u0 = *(const short8*)(h + (size_t)s0 * HD + i16 * 8);
#pragma unroll
        for (int m = 0; m < 8; m++)
            accA[m] = fmaf(bf2f((unsigned short)u0[m]), w0, accA[m]);
    }
    // rare overflow fallback (deg > MAXD): recompute weight from asrc
    if (deg > MAXD) {
        const float4 bn = *(const float4*)(adst + n * 4);
        const float bnh = (head == 0) ? bn.x : (head == 1) ? bn.y
                         : (head == 2) ? bn.z : bn.w;
        for (int jj = beg + MAXD + quad; jj < end; jj += 4) {
            int s0 = csr[jj];
            float w0 = lrelu_exp(asrc[s0 * 4 + head] + bnh) * rsel;
            short8 u0 = *(const short8*)(h + (size_t)s0 * HD + i16 * 8);
#pragma unroll
            for (int m = 0; m < 8; m++)
                accA[m] = fmaf(bf2f((unsigned short)u0[m]), w0, accA[m]);
        }
    }

#pragma unroll
    for (int m = 0; m < 8; m++) {
        accA[m] += accB[m];
        accA[m] += __shfl_xor(accA[m], 16, 64);
        accA[m] += __shfl_xor(accA[m], 32, 64);
    }
    // quads 0/1 store the two float4 halves of this chunk (constant indices)
    if (quad < 2) {
        const float4 b4 = *(const float4*)(bias + i16 * 8 + quad * 4);
        float4 st;
        if (quad == 0) {
            st.x = accA[0] + b4.x; st.y = accA[1] + b4.y;
            st.z = accA[2] + b4.z; st.w = accA[3] + b4.w;
        } else {
            st.x = accA[4] + b4.x; st.y = accA[5] + b4.y;
            st.z = accA[6] + b4.z; st.w = accA[7] + b4.w;
        }
        *(float4*)(out + (size_t)n * HD + i16 * 8 + quad * 4) = st;
    }
}

// ---------------------------------------------------------------------------
extern "C" void kernel_launch(void* const* d_in, const int* in_sizes, int n_in,
                              void* d_out, int out_size, void* d_ws, size_t ws_size,
                              hipStream_t stream)
{
    const float* x       = (const float*)d_in[0];
    const int*   ei      = (const int*)d_in[1];
    const float* W       = (const float*)d_in[2];
    const float* att_src = (const float*)d_in[3];
    const float* att_dst = (const float*)d_in[4];
    const float* bias    = (const float*)d_in[5];

    float* out   = (float*)d_out;                    // (N,128)
    float* apool = out + (size_t)NNODES * HD;        // (E,)

    // workspace layout
    unsigned short* h = (unsigned short*)d_ws;            // N*128 bf16
    float* asrc  = (float*)(h + (size_t)NNODES * HD);     // N*4
    float* adst  = asrc + NNODES * 4;                     // N*4
    float* rsumr = adst + NNODES * 4;                     // N*4
    int*   Sg    = (int*)(rsumr + NNODES * 4);            // ABLK*257
    int*   coffB = Sg + ABLK * 257 + 4;                   // N
    int*   coffE = coffB + NNODES + 4;                    // N
    int*   sbuf  = coffE + NNODES + 4;                    // ABLK*2048
    unsigned short* csr = (unsigned short*)(sbuf + (size_t)ABLK * 2048); // NBINS*CAP

    gat_main<<<GEMMB + ABLK, 256, 0, stream>>>(
        x, W, att_src, att_dst, ei, h, asrc, adst, Sg, sbuf);
    gat_bin<<<NBINS, 1024, 0, stream>>>(
        Sg, sbuf, asrc, adst, coffB, coffE, csr, rsumr);
    gat_node<<<NODEB + APOOLB, 256, 0, stream>>>(
        coffB, coffE, csr, asrc, adst, h, bias, out, rsumr, ei, apool);
}